// Round 5
// baseline (703.716 us; speedup 1.0000x reference)
//
#include <hip/hip_runtime.h>

#define N_NODES 100000
#define N_EDGES 20000
#define N_INC   1600000
#define NFEAT   256
#define NCLASS  64

#define NXCD    8
#define BCAP    208000          // per-bucket capacity (mean 200K, +19 sigma)
#define LCAP    192             // per-block LDS staging capacity per bucket

typedef int v4i __attribute__((ext_vector_type(4)));

// ============ phase 1: split incidences into 8 edge- and 8 node-buckets ====
// entry packing:  edge-bucket (key e&7): (n<<12)|(e>>3)   n:17b, e>>3:12b
//                 node-bucket (key n&7): (e<<14)|(n>>3)   e:15b, n>>3:14b
// fused: per-edge / per-node histograms (device atomics).
__global__ __launch_bounds__(256) void k_bucket(const int* __restrict__ nidx,
                                                const int* __restrict__ eidx,
                                                unsigned int* __restrict__ ebkt,
                                                unsigned int* __restrict__ nbkt,
                                                int* __restrict__ ecnt,
                                                int* __restrict__ ncnt,
                                                int* __restrict__ bcur) {
    __shared__ unsigned int stage[16][LCAP];
    __shared__ int lcnt[16];
    __shared__ int gbase[16];
    const int t = threadIdx.x;
    if (t < 16) lcnt[t] = 0;
    __syncthreads();

    const int base = blockIdx.x * 1024 + t * 4;
    if (base < N_INC) {
        const v4i e4 = __builtin_nontemporal_load((const v4i*)&eidx[base]);
        const v4i n4 = __builtin_nontemporal_load((const v4i*)&nidx[base]);
        const int es[4] = {e4.x, e4.y, e4.z, e4.w};
        const int ns[4] = {n4.x, n4.y, n4.z, n4.w};
        #pragma unroll
        for (int q = 0; q < 4; ++q) {
            const int e = es[q], n = ns[q];
            atomicAdd(&ecnt[e], 1);
            atomicAdd(&ncnt[n], 1);
            // edge-side
            {
                const int b = e & 7;
                const unsigned int pay = ((unsigned int)n << 12) | (unsigned int)(e >> 3);
                const int pos = atomicAdd(&lcnt[b], 1);
                if (pos < LCAP) stage[b][pos] = pay;
                else ebkt[(size_t)b * BCAP + atomicAdd(&bcur[b], 1)] = pay;
            }
            // node-side
            {
                const int b = 8 + (n & 7);
                const unsigned int pay = ((unsigned int)e << 14) | (unsigned int)(n >> 3);
                const int pos = atomicAdd(&lcnt[b], 1);
                if (pos < LCAP) stage[b][pos] = pay;
                else nbkt[(size_t)(b - 8) * BCAP + atomicAdd(&bcur[b], 1)] = pay;
            }
        }
    }
    __syncthreads();
    if (t < 16) gbase[t] = atomicAdd(&bcur[t], min(lcnt[t], LCAP));
    __syncthreads();
    #pragma unroll 1
    for (int k = 0; k < 16; ++k) {
        const int cnt = min(lcnt[k], LCAP);
        const int gb  = gbase[k];
        unsigned int* dst = (k < 8) ? &ebkt[(size_t)k * BCAP]
                                    : &nbkt[(size_t)(k - 8) * BCAP];
        for (int i = t; i < cnt; i += 256) dst[gb + i] = stage[k][i];
    }
}

// ============ single-block exclusive scan (int4) ===========================
__global__ __launch_bounds__(1024) void k_scan(const int* __restrict__ cnt,
                                               int* __restrict__ off,
                                               int* __restrict__ cur,
                                               int n) {
    __shared__ int part[1024];
    const int t = threadIdx.x;
    const int chunk = ((n / 4 + 1023) / 1024) * 4;
    const int lo = min(t * chunk, n);
    const int hi = min(lo + chunk, n);
    int s = 0;
    for (int i = lo; i < hi; i += 4) {
        const int4 v = *(const int4*)&cnt[i];
        s += v.x + v.y + v.z + v.w;
    }
    part[t] = s;
    __syncthreads();
    for (int d = 1; d < 1024; d <<= 1) {
        int v = (t >= d) ? part[t - d] : 0;
        __syncthreads();
        part[t] += v;
        __syncthreads();
    }
    int run = (t == 0) ? 0 : part[t - 1];
    for (int i = lo; i < hi; i += 4) {
        const int4 v = *(const int4*)&cnt[i];
        int4 o;
        o.x = run; run += v.x;
        o.y = run; run += v.y;
        o.z = run; run += v.z;
        o.w = run; run += v.w;
        *(int4*)&off[i] = o;
        *(int4*)&cur[i] = o;
    }
}

// ============ phase 2a: node-side CSR fill from node-buckets ==============
// ninc payload = edge id as u16 (< 32768)
__global__ __launch_bounds__(256) void k_fill2n(const unsigned int* __restrict__ nbkt,
                                                const int* __restrict__ bcur,
                                                int* __restrict__ ncur,
                                                unsigned short* __restrict__ ninc) {
    const int r  = blockIdx.x & 7;
    const int b8 = blockIdx.x >> 3;
    const unsigned int* bkt = &nbkt[(size_t)r * BCAP];
    const int cnt = bcur[8 + r];
    const int stride = (128 * 256) * 4;
    for (int i = (b8 * 256 + threadIdx.x) * 4; i + 4 <= cnt; i += stride) {
        const v4i u = *(const v4i*)&bkt[i];
        const unsigned int us[4] = {(unsigned int)u.x, (unsigned int)u.y,
                                    (unsigned int)u.z, (unsigned int)u.w};
        #pragma unroll
        for (int q = 0; q < 4; ++q) {
            const int n = (int)((us[q] & 0x3FFFu) << 3) | r;
            const int e = (int)(us[q] >> 14);
            ninc[atomicAdd(&ncur[n], 1)] = (unsigned short)e;
        }
    }
    // tail (cnt % 4 entries) handled by block b8==0
    if (b8 == 0 && threadIdx.x < (cnt & 3)) {
        const unsigned int u = bkt[(cnt & ~3) + threadIdx.x];
        const int n = (int)((u & 0x3FFFu) << 3) | r;
        const int e = (int)(u >> 14);
        ninc[atomicAdd(&ncur[n], 1)] = (unsigned short)e;
    }
}

// ============ phase 2b: edge-side CSR fill from edge-buckets ==============
__global__ __launch_bounds__(256) void k_fill2e(const unsigned int* __restrict__ ebkt,
                                                const int* __restrict__ bcur,
                                                int* __restrict__ ecur,
                                                int* __restrict__ einc) {
    const int r  = blockIdx.x & 7;
    const int b8 = blockIdx.x >> 3;
    const unsigned int* bkt = &ebkt[(size_t)r * BCAP];
    const int cnt = bcur[r];
    const int stride = (128 * 256) * 4;
    for (int i = (b8 * 256 + threadIdx.x) * 4; i + 4 <= cnt; i += stride) {
        const v4i u = *(const v4i*)&bkt[i];
        const unsigned int us[4] = {(unsigned int)u.x, (unsigned int)u.y,
                                    (unsigned int)u.z, (unsigned int)u.w};
        #pragma unroll
        for (int q = 0; q < 4; ++q) {
            const int e = (int)((us[q] & 0xFFFu) << 3) | r;
            const int n = (int)(us[q] >> 12);
            einc[atomicAdd(&ecur[e], 1)] = n;
        }
    }
    if (b8 == 0 && threadIdx.x < (cnt & 3)) {
        const unsigned int u = bkt[(cnt & ~3) + threadIdx.x];
        const int e = (int)((u & 0xFFFu) << 3) | r;
        const int n = (int)(u >> 12);
        einc[atomicAdd(&ecur[e], 1)] = n;
    }
}

// ============ xw = x @ W  (fp32 vector GEMM, 64x64 tile) ===================
__global__ __launch_bounds__(256) void k_gemm(const float* __restrict__ x,
                                              const float* __restrict__ W,
                                              float* __restrict__ xw) {
    __shared__ float xs[64][68];
    __shared__ float wt[64][64];
    const int t  = threadIdx.x;
    const int tr = t >> 4;
    const int tc = t & 15;
    const int block_row = blockIdx.x * 64;

    float acc[4][4] = {};

    for (int k0 = 0; k0 < NFEAT; k0 += 64) {
        {
            const int rr = t >> 2;
            const int q  = t & 3;
            const int grow = block_row + rr;
            #pragma unroll
            for (int it = 0; it < 4; ++it) {
                const int kk = q * 4 + it * 16;
                float4 v = make_float4(0.f, 0.f, 0.f, 0.f);
                if (grow < N_NODES)
                    v = *(const float4*)&x[(size_t)grow * NFEAT + k0 + kk];
                xs[kk + 0][rr] = v.x;
                xs[kk + 1][rr] = v.y;
                xs[kk + 2][rr] = v.z;
                xs[kk + 3][rr] = v.w;
            }
        }
        {
            #pragma unroll
            for (int it = 0; it < 4; ++it) {
                const int k = tr + it * 16;
                *(float4*)&wt[k][tc * 4] =
                    *(const float4*)&W[(size_t)(k0 + k) * NCLASS + tc * 4];
            }
        }
        __syncthreads();

        #pragma unroll 16
        for (int kk = 0; kk < 64; ++kk) {
            const float4 xv = *(const float4*)&xs[kk][tr * 4];
            const float4 wv = *(const float4*)&wt[kk][tc * 4];
            const float xa[4] = {xv.x, xv.y, xv.z, xv.w};
            const float wa[4] = {wv.x, wv.y, wv.z, wv.w};
            #pragma unroll
            for (int i2 = 0; i2 < 4; ++i2)
                #pragma unroll
                for (int j2 = 0; j2 < 4; ++j2)
                    acc[i2][j2] = fmaf(xa[i2], wa[j2], acc[i2][j2]);
        }
        __syncthreads();
    }

    #pragma unroll
    for (int i2 = 0; i2 < 4; ++i2) {
        const int r = block_row + tr * 4 + i2;
        if (r < N_NODES) {
            float4 v = make_float4(acc[i2][0], acc[i2][1], acc[i2][2], acc[i2][3]);
            *(float4*)&xw[(size_t)r * NCLASS + tc * 4] = v;
        }
    }
}

// ============ per-edge pull gather (one wave per edge, lane=channel) =======
__global__ __launch_bounds__(256) void k_edge_gather(const int* __restrict__ einc,
                                                     const int* __restrict__ eoff,
                                                     const int* __restrict__ ecnt,
                                                     const float* __restrict__ xw,
                                                     float* __restrict__ e_feat) {
    const int wave = (blockIdx.x * 256 + threadIdx.x) >> 6;
    const int lane = threadIdx.x & 63;
    if (wave >= N_EDGES) return;
    const int base = eoff[wave];
    const int deg  = ecnt[wave];
    float a0 = 0.f, a1 = 0.f, a2 = 0.f, a3 = 0.f;
    int j = base;
    const int end = base + deg;
    for (; j + 4 <= end; j += 4) {
        const int n0 = einc[j], n1 = einc[j + 1], n2 = einc[j + 2], n3 = einc[j + 3];
        a0 += xw[(size_t)n0 * NCLASS + lane];
        a1 += xw[(size_t)n1 * NCLASS + lane];
        a2 += xw[(size_t)n2 * NCLASS + lane];
        a3 += xw[(size_t)n3 * NCLASS + lane];
    }
    for (; j < end; ++j) a0 += xw[(size_t)einc[j] * NCLASS + lane];
    const float s = (a0 + a1) + (a2 + a3);
    e_feat[(size_t)wave * NCLASS + lane] = (deg > 0) ? s / (float)deg : 0.f;
}

// ============ per-node pull gather + Dinv + bias + relu ====================
__global__ __launch_bounds__(256) void k_node_gather(const unsigned short* __restrict__ ninc,
                                                     const int* __restrict__ noff,
                                                     const int* __restrict__ ncnt,
                                                     const float* __restrict__ e_feat,
                                                     const float* __restrict__ b,
                                                     float* __restrict__ out) {
    const int wave = (blockIdx.x * 256 + threadIdx.x) >> 6;
    const int lane = threadIdx.x & 63;
    if (wave >= N_NODES) return;
    const int base = noff[wave];
    const int deg  = ncnt[wave];
    float a0 = 0.f, a1 = 0.f, a2 = 0.f, a3 = 0.f;
    int j = base;
    const int end = base + deg;
    for (; j + 4 <= end; j += 4) {
        const int e0 = ninc[j], e1 = ninc[j + 1], e2 = ninc[j + 2], e3 = ninc[j + 3];
        a0 += e_feat[(size_t)e0 * NCLASS + lane];
        a1 += e_feat[(size_t)e1 * NCLASS + lane];
        a2 += e_feat[(size_t)e2 * NCLASS + lane];
        a3 += e_feat[(size_t)e3 * NCLASS + lane];
    }
    for (; j < end; ++j) a0 += e_feat[(size_t)ninc[j] * NCLASS + lane];
    const float s = (a0 + a1) + (a2 + a3);
    const float r = (deg > 0) ? s / (float)deg : 0.f;
    out[(size_t)wave * NCLASS + lane] = fmaxf(r + b[lane], 0.f);
}

extern "C" void kernel_launch(void* const* d_in, const int* in_sizes, int n_in,
                              void* d_out, int out_size, void* d_ws, size_t ws_size,
                              hipStream_t stream) {
    const float* x    = (const float*)d_in[0];
    const int*   adj  = (const int*)d_in[1];
    const float* W    = (const float*)d_in[2];
    const float* bias = (const float*)d_in[3];
    const int* nidx = adj;            // adj[0]: node index per incidence
    const int* eidx = adj + N_INC;    // adj[1]: edge index per incidence
    float* out = (float*)d_out;

    // ---- workspace layout (17,952,064 bytes max-live) ----
    char* ws = (char*)d_ws;
    unsigned int*   ebkt = (unsigned int*)(ws);                   // 6,656,000
    unsigned int*   nbkt = (unsigned int*)(ws + 6656000);         // 6,656,000
    unsigned short* ninc = (unsigned short*)(ws + 13312000);      // 3,200,000
    int* ecnt = (int*)(ws + 16512000);                            //    80,000
    int* ncnt = (int*)(ws + 16592000);                            //   400,000
    int* bcur = (int*)(ws + 16992000);                            //        64
    int* eoff = (int*)(ws + 16992064);                            //    80,000
    int* ecur = (int*)(ws + 17072064);                            //    80,000
    int* noff = (int*)(ws + 17152064);                            //   400,000
    int* ncur = (int*)(ws + 17552064);                            //   400,000
    // overlays (regions dead by the time these go live):
    int*   einc   = (int*)(ws + 6656000);    // over nbkt (dead after k_fill2n)
    float* e_feat = (float*)(ws);            // over ebkt (dead after k_fill2e)

    // zero histograms + bucket cursors (contiguous: ecnt,ncnt,bcur)
    hipMemsetAsync(ecnt, 0, 480064, stream);

    // phase 1: bucket split + fused degree histograms
    k_bucket<<<(N_INC + 1023) / 1024, 256, 0, stream>>>(nidx, eidx, ebkt, nbkt,
                                                        ecnt, ncnt, bcur);

    // offsets + fill cursors
    k_scan<<<1, 1024, 0, stream>>>(ecnt, eoff, ecur, N_EDGES);
    k_scan<<<1, 1024, 0, stream>>>(ncnt, noff, ncur, N_NODES);

    // phase 2: per-XCD CSR fills (node side first: einc overlays nbkt)
    k_fill2n<<<8 * 128, 256, 0, stream>>>(nbkt, bcur, ncur, ninc);
    k_fill2e<<<8 * 128, 256, 0, stream>>>(ebkt, bcur, ecur, einc);

    // xw = x @ W  (stored in d_out; consumed before out is overwritten)
    k_gemm<<<(N_NODES + 63) / 64, 256, 0, stream>>>(x, W, out);

    // edge aggregation (pull), fused * Binv   (e_feat overlays ebkt)
    k_edge_gather<<<(N_EDGES * 64) / 256, 256, 0, stream>>>(einc, eoff, ecnt, out, e_feat);

    // node aggregation (pull), fused * Dinv + bias + relu
    k_node_gather<<<(N_NODES * 64) / 256, 256, 0, stream>>>(ninc, noff, ncnt, e_feat, bias, out);
}

// Round 6
// 533.836 us; speedup vs baseline: 1.3182x; 1.3182x over previous
//
#include <hip/hip_runtime.h>

#define N_NODES 100000
#define N_EDGES 20000
#define N_INC   1600000
#define NFEAT   256
#define NCLASS  64

#define ELOC 2500            // edges per range (e&7)
#define NLOC 12500           // nodes per range (n&7)
#define BCAP 201728          // per-bucket capacity (mean 200K + ~4 sigma, 64B-aligned)
#define EPB  8               // blocks per bucket in hist/fill
#define LCAP 192             // per-block LDS staging per bucket in k_bucket

typedef int v4i __attribute__((ext_vector_type(4)));

// ============ phase 1: split incidences into 8 edge- and 8 node-buckets ====
// edge-bucket (key e&7): payload (n<<12)|(e>>3)   n:17b, e>>3:12b
// node-bucket (key n&7): payload (e<<14)|(n>>3)   e:15b, n>>3:14b
// Only bulk cursor reservation atomics (~25K total), no histograms.
__global__ __launch_bounds__(256) void k_bucket(const int* __restrict__ nidx,
                                                const int* __restrict__ eidx,
                                                unsigned int* __restrict__ ebkt,
                                                unsigned int* __restrict__ nbkt,
                                                int* __restrict__ bcur) {
    __shared__ unsigned int stage[16][LCAP];
    __shared__ int lcnt[16];
    __shared__ int gbase[16];
    const int t = threadIdx.x;
    if (t < 16) lcnt[t] = 0;
    __syncthreads();

    const int base = blockIdx.x * 1024 + t * 4;
    if (base < N_INC) {
        const v4i e4 = __builtin_nontemporal_load((const v4i*)&eidx[base]);
        const v4i n4 = __builtin_nontemporal_load((const v4i*)&nidx[base]);
        const int es[4] = {e4.x, e4.y, e4.z, e4.w};
        const int ns[4] = {n4.x, n4.y, n4.z, n4.w};
        #pragma unroll
        for (int q = 0; q < 4; ++q) {
            const int e = es[q], n = ns[q];
            {
                const int b = e & 7;
                const unsigned int pay = ((unsigned int)n << 12) | (unsigned int)(e >> 3);
                const int pos = atomicAdd(&lcnt[b], 1);
                if (pos < LCAP) stage[b][pos] = pay;
                else ebkt[(size_t)b * BCAP + atomicAdd(&bcur[b], 1)] = pay;
            }
            {
                const int b = 8 + (n & 7);
                const unsigned int pay = ((unsigned int)e << 14) | (unsigned int)(n >> 3);
                const int pos = atomicAdd(&lcnt[b], 1);
                if (pos < LCAP) stage[b][pos] = pay;
                else nbkt[(size_t)(b - 8) * BCAP + atomicAdd(&bcur[b], 1)] = pay;
            }
        }
    }
    __syncthreads();
    if (t < 16) gbase[t] = atomicAdd(&bcur[t], min(lcnt[t], LCAP));
    __syncthreads();
    #pragma unroll 1
    for (int k = 0; k < 16; ++k) {
        const int cnt = min(lcnt[k], LCAP);
        const int gb  = gbase[k];
        unsigned int* dst = (k < 8) ? &ebkt[(size_t)k * BCAP]
                                    : &nbkt[(size_t)(k - 8) * BCAP];
        for (int i = t; i < cnt; i += 256) dst[gb + i] = stage[k][i];
    }
}

// ============ per-(bucket,block) LDS histogram → u16 per-block hists =======
// grid = 8 buckets x EPB blocks; dynamic LDS = SZ u32 counters.
__global__ __launch_bounds__(256) void k_hist(const unsigned int* __restrict__ bkt,
                                              const int* __restrict__ bcur,
                                              int cur_off,
                                              unsigned short* __restrict__ hist,
                                              int SZ, unsigned int mask) {
    extern __shared__ unsigned int h[];
    const int r = blockIdx.x & 7, b = blockIdx.x >> 3;
    const int t = threadIdx.x;
    for (int i = t; i < SZ; i += 256) h[i] = 0;
    __syncthreads();
    const int cnt = bcur[cur_off + r];
    const int sz  = (cnt + EPB - 1) / EPB;
    const int lo  = b * sz, hi = min(lo + sz, cnt);
    const unsigned int* B = &bkt[(size_t)r * BCAP];
    for (int i = lo + t; i < hi; i += 256)
        atomicAdd(&h[B[i] & mask], 1u);
    __syncthreads();
    unsigned short* H = &hist[(size_t)(r * EPB + b) * SZ];
    for (int i = t; i < SZ; i += 256) H[i] = (unsigned short)h[i];
}

// ============ per-counter exclusive prefix over the EPB block hists ========
// hist[r][b][i] (u16) -> exclusive prefix over b (in place); total -> cnt_perm
__global__ __launch_bounds__(256) void k_colscan(unsigned short* __restrict__ hist,
                                                 int* __restrict__ cnt_perm, int SZ) {
    const int g = blockIdx.x * 256 + threadIdx.x;
    if (g >= 8 * SZ) return;
    const int r = g / SZ, i = g - r * SZ;
    unsigned short* H = hist + (size_t)r * EPB * SZ + i;
    unsigned int run = 0;
    #pragma unroll
    for (int b = 0; b < EPB; ++b) {
        const unsigned int v = H[(size_t)b * SZ];
        H[(size_t)b * SZ] = (unsigned short)run;
        run += v;
    }
    cnt_perm[g] = (int)run;
}

// ============ single-block exclusive scan (int4), offsets only =============
__global__ __launch_bounds__(1024) void k_scan(const int* __restrict__ cnt,
                                               int* __restrict__ off, int n) {
    __shared__ int part[1024];
    const int t = threadIdx.x;
    const int chunk = ((n / 4 + 1023) / 1024) * 4;
    const int lo = min(t * chunk, n);
    const int hi = min(lo + chunk, n);
    int s = 0;
    for (int i = lo; i < hi; i += 4) {
        const int4 v = *(const int4*)&cnt[i];
        s += v.x + v.y + v.z + v.w;
    }
    part[t] = s;
    __syncthreads();
    for (int d = 1; d < 1024; d <<= 1) {
        int v = (t >= d) ? part[t - d] : 0;
        __syncthreads();
        part[t] += v;
        __syncthreads();
    }
    int run = (t == 0) ? 0 : part[t - 1];
    for (int i = lo; i < hi; i += 4) {
        const int4 v = *(const int4*)&cnt[i];
        int4 o;
        o.x = run; run += v.x;
        o.y = run; run += v.y;
        o.z = run; run += v.z;
        o.w = run; run += v.w;
        *(int4*)&off[i] = o;
    }
}

// ============ fills: LDS cursors = off + per-block prefix; LDS atomics only
__global__ __launch_bounds__(256) void k_fill3n(const unsigned int* __restrict__ nbkt,
                                                const int* __restrict__ bcur,
                                                const unsigned short* __restrict__ nhist,
                                                const int* __restrict__ noff,
                                                unsigned short* __restrict__ ninc) {
    __shared__ unsigned int lb[NLOC];
    const int r = blockIdx.x & 7, b = blockIdx.x >> 3;
    const int t = threadIdx.x;
    const unsigned short* H = &nhist[(size_t)(r * EPB + b) * NLOC];
    const int* O = &noff[r * NLOC];
    for (int i = t; i < NLOC; i += 256) lb[i] = (unsigned int)O[i] + H[i];
    __syncthreads();
    const int cnt = bcur[8 + r];
    const int sz  = (cnt + EPB - 1) / EPB;
    const int lo  = b * sz, hi = min(lo + sz, cnt);
    const unsigned int* B = &nbkt[(size_t)r * BCAP];
    for (int i = lo + t; i < hi; i += 256) {
        const unsigned int u = B[i];
        const unsigned int pos = atomicAdd(&lb[u & 0x3FFFu], 1u);
        ninc[pos] = (unsigned short)(u >> 14);
    }
}

__global__ __launch_bounds__(256) void k_fill3e(const unsigned int* __restrict__ ebkt,
                                                const int* __restrict__ bcur,
                                                const unsigned short* __restrict__ ehist,
                                                const int* __restrict__ eoff,
                                                int* __restrict__ einc) {
    __shared__ unsigned int lb[ELOC];
    const int r = blockIdx.x & 7, b = blockIdx.x >> 3;
    const int t = threadIdx.x;
    const unsigned short* H = &ehist[(size_t)(r * EPB + b) * ELOC];
    const int* O = &eoff[r * ELOC];
    for (int i = t; i < ELOC; i += 256) lb[i] = (unsigned int)O[i] + H[i];
    __syncthreads();
    const int cnt = bcur[r];
    const int sz  = (cnt + EPB - 1) / EPB;
    const int lo  = b * sz, hi = min(lo + sz, cnt);
    const unsigned int* B = &ebkt[(size_t)r * BCAP];
    for (int i = lo + t; i < hi; i += 256) {
        const unsigned int u = B[i];
        const unsigned int pos = atomicAdd(&lb[u & 0xFFFu], 1u);
        einc[pos] = (int)(u >> 12);
    }
}

// ============ xw = x @ W  (fp32 vector GEMM, 64x64 tile) ===================
__global__ __launch_bounds__(256) void k_gemm(const float* __restrict__ x,
                                              const float* __restrict__ W,
                                              float* __restrict__ xw) {
    __shared__ float xs[64][68];
    __shared__ float wt[64][64];
    const int t  = threadIdx.x;
    const int tr = t >> 4;
    const int tc = t & 15;
    const int block_row = blockIdx.x * 64;

    float acc[4][4] = {};

    for (int k0 = 0; k0 < NFEAT; k0 += 64) {
        {
            const int rr = t >> 2;
            const int q  = t & 3;
            const int grow = block_row + rr;
            #pragma unroll
            for (int it = 0; it < 4; ++it) {
                const int kk = q * 4 + it * 16;
                float4 v = make_float4(0.f, 0.f, 0.f, 0.f);
                if (grow < N_NODES)
                    v = *(const float4*)&x[(size_t)grow * NFEAT + k0 + kk];
                xs[kk + 0][rr] = v.x;
                xs[kk + 1][rr] = v.y;
                xs[kk + 2][rr] = v.z;
                xs[kk + 3][rr] = v.w;
            }
        }
        {
            #pragma unroll
            for (int it = 0; it < 4; ++it) {
                const int k = tr + it * 16;
                *(float4*)&wt[k][tc * 4] =
                    *(const float4*)&W[(size_t)(k0 + k) * NCLASS + tc * 4];
            }
        }
        __syncthreads();

        #pragma unroll 16
        for (int kk = 0; kk < 64; ++kk) {
            const float4 xv = *(const float4*)&xs[kk][tr * 4];
            const float4 wv = *(const float4*)&wt[kk][tc * 4];
            const float xa[4] = {xv.x, xv.y, xv.z, xv.w};
            const float wa[4] = {wv.x, wv.y, wv.z, wv.w};
            #pragma unroll
            for (int i2 = 0; i2 < 4; ++i2)
                #pragma unroll
                for (int j2 = 0; j2 < 4; ++j2)
                    acc[i2][j2] = fmaf(xa[i2], wa[j2], acc[i2][j2]);
        }
        __syncthreads();
    }

    #pragma unroll
    for (int i2 = 0; i2 < 4; ++i2) {
        const int r = block_row + tr * 4 + i2;
        if (r < N_NODES) {
            float4 v = make_float4(acc[i2][0], acc[i2][1], acc[i2][2], acc[i2][3]);
            *(float4*)&xw[(size_t)r * NCLASS + tc * 4] = v;
        }
    }
}

// ============ per-edge pull gather (one wave per edge, lane=channel) =======
__global__ __launch_bounds__(256) void k_edge_gather(const int* __restrict__ einc,
                                                     const int* __restrict__ eoff,
                                                     const int* __restrict__ ecnt,
                                                     const float* __restrict__ xw,
                                                     float* __restrict__ e_feat) {
    const int wave = (blockIdx.x * 256 + threadIdx.x) >> 6;
    const int lane = threadIdx.x & 63;
    if (wave >= N_EDGES) return;
    const int idx  = (wave & 7) * ELOC + (wave >> 3);   // range-major perm
    const int base = eoff[idx];
    const int deg  = ecnt[idx];
    float a0 = 0.f, a1 = 0.f, a2 = 0.f, a3 = 0.f;
    int j = base;
    const int end = base + deg;
    for (; j + 4 <= end; j += 4) {
        const int n0 = einc[j], n1 = einc[j + 1], n2 = einc[j + 2], n3 = einc[j + 3];
        a0 += xw[(size_t)n0 * NCLASS + lane];
        a1 += xw[(size_t)n1 * NCLASS + lane];
        a2 += xw[(size_t)n2 * NCLASS + lane];
        a3 += xw[(size_t)n3 * NCLASS + lane];
    }
    for (; j < end; ++j) a0 += xw[(size_t)einc[j] * NCLASS + lane];
    const float s = (a0 + a1) + (a2 + a3);
    e_feat[(size_t)wave * NCLASS + lane] = (deg > 0) ? s / (float)deg : 0.f;
}

// ============ per-node pull gather + Dinv + bias + relu ====================
__global__ __launch_bounds__(256) void k_node_gather(const unsigned short* __restrict__ ninc,
                                                     const int* __restrict__ noff,
                                                     const int* __restrict__ ncnt,
                                                     const float* __restrict__ e_feat,
                                                     const float* __restrict__ b,
                                                     float* __restrict__ out) {
    const int wave = (blockIdx.x * 256 + threadIdx.x) >> 6;
    const int lane = threadIdx.x & 63;
    if (wave >= N_NODES) return;
    const int idx  = (wave & 7) * NLOC + (wave >> 3);   // range-major perm
    const int base = noff[idx];
    const int deg  = ncnt[idx];
    float a0 = 0.f, a1 = 0.f, a2 = 0.f, a3 = 0.f;
    int j = base;
    const int end = base + deg;
    for (; j + 4 <= end; j += 4) {
        const int e0 = ninc[j], e1 = ninc[j + 1], e2 = ninc[j + 2], e3 = ninc[j + 3];
        a0 += e_feat[(size_t)e0 * NCLASS + lane];
        a1 += e_feat[(size_t)e1 * NCLASS + lane];
        a2 += e_feat[(size_t)e2 * NCLASS + lane];
        a3 += e_feat[(size_t)e3 * NCLASS + lane];
    }
    for (; j < end; ++j) a0 += e_feat[(size_t)ninc[j] * NCLASS + lane];
    const float s = (a0 + a1) + (a2 + a3);
    const float r = (deg > 0) ? s / (float)deg : 0.f;
    out[(size_t)wave * NCLASS + lane] = fmaxf(r + b[lane], 0.f);
}

extern "C" void kernel_launch(void* const* d_in, const int* in_sizes, int n_in,
                              void* d_out, int out_size, void* d_ws, size_t ws_size,
                              hipStream_t stream) {
    const float* x    = (const float*)d_in[0];
    const int*   adj  = (const int*)d_in[1];
    const float* W    = (const float*)d_in[2];
    const float* bias = (const float*)d_in[3];
    const int* nidx = adj;            // adj[0]: node index per incidence
    const int* eidx = adj + N_INC;    // adj[1]: edge index per incidence
    float* out = (float*)d_out;

    // ---- workspace layout (18,990,656 bytes max-live) ----
    char* ws = (char*)d_ws;
    unsigned int*   ebkt  = (unsigned int*)(ws);                    // 6,455,296
    unsigned int*   nbkt  = (unsigned int*)(ws + 6455296);          // 6,455,296
    unsigned short* ninc  = (unsigned short*)(ws + 12910592);       // 3,200,000
    unsigned short* nhist = (unsigned short*)(ws + 16110592);       // 1,600,000
    unsigned short* ehist = (unsigned short*)(ws + 17710592);       //   320,000
    int* ncnt = (int*)(ws + 18030592);                              //   400,000
    int* noff = (int*)(ws + 18430592);                              //   400,000
    int* ecnt = (int*)(ws + 18830592);                              //    80,000
    int* eoff = (int*)(ws + 18910592);                              //    80,000
    int* bcur = (int*)(ws + 18990592);                              //        64
    // overlays (dead regions at go-live time):
    int*   einc   = (int*)(ws + 6455296);   // over nbkt (dead after k_fill3n)
    float* e_feat = (float*)(ws);           // over ebkt (dead after k_fill3e)

    // zero bucket cursors only
    hipMemsetAsync(bcur, 0, 64, stream);

    // phase 1: bucket split (bulk reservation, no per-incidence atomics)
    k_bucket<<<(N_INC + 1023) / 1024, 256, 0, stream>>>(nidx, eidx, ebkt, nbkt, bcur);

    // phase 2: per-block LDS histograms (zero device atomics)
    k_hist<<<8 * EPB, 256, ELOC * 4, stream>>>(ebkt, bcur, 0, ehist, ELOC, 0xFFFu);
    k_hist<<<8 * EPB, 256, NLOC * 4, stream>>>(nbkt, bcur, 8, nhist, NLOC, 0x3FFFu);

    // phase 3: per-counter block-prefix + degree totals, then global offsets
    k_colscan<<<(8 * ELOC + 255) / 256, 256, 0, stream>>>(ehist, ecnt, ELOC);
    k_colscan<<<(8 * NLOC + 255) / 256, 256, 0, stream>>>(nhist, ncnt, NLOC);
    k_scan<<<1, 1024, 0, stream>>>(ecnt, eoff, N_EDGES);
    k_scan<<<1, 1024, 0, stream>>>(ncnt, noff, N_NODES);

    // phase 4: atomic-free CSR fills (LDS cursors; node side first, einc overlays nbkt)
    k_fill3n<<<8 * EPB, 256, 0, stream>>>(nbkt, bcur, nhist, noff, ninc);
    k_fill3e<<<8 * EPB, 256, 0, stream>>>(ebkt, bcur, ehist, eoff, einc);

    // xw = x @ W  (stored in d_out; consumed before out is overwritten)
    k_gemm<<<(N_NODES + 63) / 64, 256, 0, stream>>>(x, W, out);

    // edge aggregation (pull), fused * Binv   (e_feat overlays ebkt)
    k_edge_gather<<<(N_EDGES * 64) / 256, 256, 0, stream>>>(einc, eoff, ecnt, out, e_feat);

    // node aggregation (pull), fused * Dinv + bias + relu
    k_node_gather<<<(N_NODES * 64) / 256, 256, 0, stream>>>(ninc, noff, ncnt, e_feat, bias, out);
}